// Round 10
// baseline (674.369 us; speedup 1.0000x reference)
//
#include <hip/hip_runtime.h>
#include <stdint.h>

#define H     1024
#define K2    2048
#define NTOT  5120
#define BATCH 64
#define BM 128
#define BN 128
#define BK 64

typedef unsigned short u16;
typedef __attribute__((ext_vector_type(8))) short short8;
typedef __attribute__((ext_vector_type(4))) float floatx4;

__device__ __forceinline__ float bf2f(u16 u) {
    return __uint_as_float(((uint32_t)u) << 16);
}
__device__ __forceinline__ u16 f2bf(float f) {
    uint32_t u = __float_as_uint(f);
    u += 0x7fffu + ((u >> 16) & 1u);
    return (u16)(u >> 16);
}
__device__ __forceinline__ uint32_t pk2(float lo, float hi) {
    return (uint32_t)f2bf(lo) | ((uint32_t)f2bf(hi) << 16);
}
__device__ __forceinline__ float sigf(float x) {
    return 1.0f / (1.0f + __expf(-x));
}
__device__ __forceinline__ float tanh_(float x) {
    float e = __expf(-2.0f * fabsf(x));
    float r = (1.0f - e) / (1.0f + e);
    return copysignf(r, x);
}

// ---- pack weights (fp32 in) -> bf16 WT[n][k]; k<1024 from W, else U ----
__global__ void pack_weights(const float* __restrict__ Wio, const float* __restrict__ Uio,
                             const float* __restrict__ Wfl, const float* __restrict__ Ufl,
                             const float* __restrict__ Wfr, const float* __restrict__ Ufr,
                             u16* __restrict__ WT) {
    __shared__ u16 tile[32][33];
    int k0 = blockIdx.x * 32;
    int n0 = blockIdx.y * 32;
    const float *Wp, *Up; int ncols, nloc;
    if (n0 < 3072)      { Wp = Wio; Up = Uio; ncols = 3072; nloc = n0; }
    else if (n0 < 4096) { Wp = Wfl; Up = Ufl; ncols = 1024; nloc = n0 - 3072; }
    else                { Wp = Wfr; Up = Ufr; ncols = 1024; nloc = n0 - 4096; }
    int t = threadIdx.x;
    int c = t & 31, r = t >> 5;
#pragma unroll
    for (int i = 0; i < 4; ++i) {
        int rr = r + i * 8;
        int k = k0 + rr;
        float v = (k < 1024) ? Wp[(long)k * ncols + nloc + c]
                             : Up[(long)(k - 1024) * ncols + nloc + c];
        tile[rr][c] = f2bf(v);
    }
    __syncthreads();
#pragma unroll
    for (int i = 0; i < 4; ++i) {
        int rr = r + i * 8;
        WT[(long)(n0 + rr) * K2 + k0 + c] = tile[c][rr];
    }
}

// ---- leaf gather + fp32->bf16: leaf[node][d] = emb[tokens[node]][d] ----
__global__ void leaf_pack(const int* __restrict__ tokens, const float* __restrict__ emb,
                          u16* __restrict__ leaf) {
    int idx = blockIdx.x * 256 + threadIdx.x;   // 16384 blocks -> 4,194,304 float4
    int node = idx >> 8;
    int d4 = idx & 255;
    int tok = tokens[node];
    float4 v = ((const float4*)emb)[(long)tok * 256 + d4];
    uint2 o; o.x = pk2(v.x, v.y); o.y = pk2(v.z, v.w);
    ((uint2*)leaf)[(long)node * 256 + d4] = o;
}

// ---- GEMM (m97 structure, 128x128) legacy fallback ----
__global__ void gemm_bt(const u16* __restrict__ A, const u16* __restrict__ BT,
                        float* __restrict__ G, int mc) {
    __shared__ __align__(16) u16 AsBs[16896];   // 33,792 B; K-loop: As|Bs, epilogue: epi
    u16* As = AsBs;
    u16* Bs = AsBs + 8192;
    float* epi = (float*)AsBs;                  // 64 x 132 fp32
    int tid  = threadIdx.x;
    int lane = tid & 63;
    int w    = tid >> 6;
    int wm   = w >> 1, wn = w & 1;
    int rowTile = blockIdx.x * BM;
    int n0      = blockIdx.y * BN;

    const u16* asrc[4];
    const u16* bsrc[4];
#pragma unroll
    for (int cc = 0; cc < 4; ++cc) {
        int r = cc * 32 + w * 8 + (lane >> 3);
        int j = rowTile + r; if (j >= mc) j = mc - 1;
        asrc[cc] = A + (long)j * K2 + (lane & 7) * 8;
        bsrc[cc] = BT + (long)(n0 + r) * K2 + (lane & 7) * 8;
    }

    floatx4 acc[4][4];
#pragma unroll
    for (int mt = 0; mt < 4; ++mt)
#pragma unroll
        for (int nt = 0; nt < 4; ++nt)
            acc[mt][nt] = (floatx4){0.f, 0.f, 0.f, 0.f};

    for (int k0 = 0; k0 < K2; k0 += BK) {
#pragma unroll
        for (int cc = 0; cc < 4; ++cc) {
            __builtin_amdgcn_global_load_lds(
                (const __attribute__((address_space(1))) void*)(asrc[cc] + k0),
                (__attribute__((address_space(3))) void*)(As + cc * 2048 + w * 512), 16, 0, 0);
            __builtin_amdgcn_global_load_lds(
                (const __attribute__((address_space(1))) void*)(bsrc[cc] + k0),
                (__attribute__((address_space(3))) void*)(Bs + cc * 2048 + w * 512), 16, 0, 0);
        }
        __syncthreads();
#pragma unroll
        for (int kb = 0; kb < 2; ++kb) {
            int kfo = kb * 32 + (lane >> 4) * 8;
            short8 af[4], bfv[4];
#pragma unroll
            for (int mt = 0; mt < 4; ++mt)
                af[mt] = *(const short8*)&As[(wm * 64 + mt * 16 + (lane & 15)) * BK + kfo];
#pragma unroll
            for (int nt = 0; nt < 4; ++nt)
                bfv[nt] = *(const short8*)&Bs[(wn * 64 + nt * 16 + (lane & 15)) * BK + kfo];
#pragma unroll
            for (int mt = 0; mt < 4; ++mt)
#pragma unroll
                for (int nt = 0; nt < 4; ++nt)
                    acc[mt][nt] = __builtin_amdgcn_mfma_f32_16x16x32_bf16(
                        af[mt], bfv[nt], acc[mt][nt], 0, 0, 0);
        }
        __syncthreads();
    }

#pragma unroll
    for (int s = 0; s < 2; ++s) {
        if (wm == s) {
#pragma unroll
            for (int mt = 0; mt < 4; ++mt)
#pragma unroll
                for (int r = 0; r < 4; ++r) {
                    int lrow = mt * 16 + (lane >> 4) * 4 + r;
#pragma unroll
                    for (int nt = 0; nt < 4; ++nt)
                        epi[lrow * 132 + wn * 64 + nt * 16 + (lane & 15)] = acc[mt][nt][r];
                }
        }
        __syncthreads();
        int gr0 = rowTile + s * 64;
#pragma unroll
        for (int k = 0; k < 8; ++k) {
            int f4 = tid + k * 256;     // 0..2047 float4 slots = 64 rows x 32
            int row = f4 >> 5, c4 = f4 & 31;
            if (gr0 + row < mc) {
                float4 v = *(const float4*)&epi[row * 132 + c4 * 4];
                *(float4*)&G[(long)(gr0 + row) * NTOT + n0 + c4 * 4] = v;
            }
        }
        __syncthreads();
    }
}

// ==== FUSED 128x64-d GEMM+gates, single-buffer 5-phase, 2 blocks/CU ==========
// Same layout/staging involution/epilogue as round-9 gemmF<128>, but LDS is
// SINGLE-buffered (56 KiB -> 2 blocks/CU with __launch_bounds__(512,4)).
// Safe because each region {A, B0..B4} is read in exactly one phase; region
// X(t+1) is staged >=1 barrier after X(t)'s reads, and every barrier is
// preceded by s_waitcnt lgkmcnt(0) (raw s_barrier does NOT drain ds_reads -
// that wait is the WAR fence for the in-place overwrite).
// Per-wave FIFO (7 loads/tile; issue order B4(t)@P0, A(t+1)x2@P1, B0@P2,
// B1@P3, B2+B3@P4; consume order A,B0 | B1 | B2 | B3 | B4):
//   steady waits: P0 vmcnt(3), P1 (3), P2 (4), P3 (4), P4 (4)
//   last tile:    P0 (3),      P1 (3), P2 (2), P3 (1), P4 (0)
// Prologue stages A(0)+B0..B3(0) only (B4(0) staged at t=0 P0). 4-6 loads
// always in flight; no main-loop drain to 0.
#define SWZ2(r) (((r) >> 1) & 3)

#define GP_WAIT(VM)                                                                  \
    asm volatile("s_waitcnt vmcnt(" #VM ") lgkmcnt(0)\n\ts_barrier" ::: "memory")

__global__ __launch_bounds__(512, 4) void gemmP128(const u16* __restrict__ A,
                                                   const u16* __restrict__ BT,
                                                   const float* __restrict__ bio,
                                                   const float* __restrict__ bfl,
                                                   const float* __restrict__ bfr,
                                                   const void* __restrict__ c_in,
                                                   void* __restrict__ c_out, int c_bf16,
                                                   float* __restrict__ outF,
                                                   u16* __restrict__ hnext,
                                                   int lp, int level_off, int gm) {
    __shared__ __align__(16) u16 lds[28672];    // 56 KiB: A [ks:2]8KB | B [g:5][ks:2]4KB
    const int tid  = threadIdx.x;
    const int lane = tid & 63;
    const int w    = tid >> 6;
    const int wm   = w >> 1;    // 0..3
    const int wd   = w & 1;     // 0..1

    // 2D XCD chunking (gm%4==0 at all call sites): 8 d-tiles x gm/4 row-tiles
    // per XCD -> per-k-tile working set L2-resident; A fetched by ONE XCD.
    int f = blockIdx.x;
    int xcd = f & 7, c = f >> 3;
    int by = (xcd & 1) * 8 + (c & 7);            // d-tile 0..15
    int bx = (xcd >> 1) * (gm >> 2) + (c >> 3);  // row-tile 0..gm-1
    long rowTile = (long)bx * 128;
    int d0 = by * 64;

    const u16* srcA[2];
    {
        int rr_ = w * 16 + (lane >> 2);
        int ck_ = ((lane & 3) ^ SWZ2(rr_)) * 8;
#pragma unroll
        for (int cc = 0; cc < 2; ++cc)
            srcA[cc] = A + (rowTile + rr_) * (long)K2 + cc * 32 + ck_;
    }
    const u16* srcB[5];
    {
        int sr_ = (w >> 1) * 16 + (lane >> 2);
        int ck_ = ((lane & 3) ^ SWZ2(sr_)) * 8;
#pragma unroll
        for (int g = 0; g < 5; ++g)
            srcB[g] = BT + (long)(g * 1024 + d0 + sr_) * K2 + (w & 1) * 32 + ck_;
    }

    const int qv = lane >> 4;
    int rA[2];
#pragma unroll
    for (int mf = 0; mf < 2; ++mf) {
        int rg = wm * 32 + mf * 16 + (lane & 15);           // 0..127
        rA[mf] = rg * 32 + ((qv ^ SWZ2(rg)) * 8);
    }
    int rB[2];
#pragma unroll
    for (int sub = 0; sub < 2; ++sub) {
        int rb = wd * 32 + sub * 16 + (lane & 15);          // row in 64-row strip
        rB[sub] = rb * 32 + ((qv ^ SWZ2(rb)) * 8);
    }

    floatx4 acc[2][10];
#pragma unroll
    for (int mf = 0; mf < 2; ++mf)
#pragma unroll
        for (int nf = 0; nf < 10; ++nf)
            acc[mf][nf] = (floatx4){0.f, 0.f, 0.f, 0.f};

#define GP_STG_A(TT)                                                                 \
    do {                                                                             \
        _Pragma("unroll")                                                            \
        for (int cc = 0; cc < 2; ++cc)                                               \
            __builtin_amdgcn_global_load_lds(                                        \
                (const __attribute__((address_space(1))) void*)(srcA[cc] + (TT) * 64),\
                (__attribute__((address_space(3))) void*)(lds + cc * 4096 + tid * 8), 16, 0, 0); \
    } while (0)

#define GP_STG_B(TT, GG)                                                             \
    __builtin_amdgcn_global_load_lds(                                                \
        (const __attribute__((address_space(1))) void*)(srcB[GG] + (TT) * 64),       \
        (__attribute__((address_space(3))) void*)(lds + 8192 + (GG) * 4096 + (w & 1) * 2048 + (w >> 1) * 512 + lane * 8), 16, 0, 0)

#define GP_MFMA(GG)                                                                  \
    do {                                                                             \
        __builtin_amdgcn_s_setprio(1);                                               \
        _Pragma("unroll")                                                            \
        for (int ks = 0; ks < 2; ++ks)                                               \
            _Pragma("unroll")                                                        \
            for (int mf = 0; mf < 2; ++mf)                                           \
                _Pragma("unroll")                                                    \
                for (int sub = 0; sub < 2; ++sub)                                    \
                    acc[mf][(GG) * 2 + sub] = __builtin_amdgcn_mfma_f32_16x16x32_bf16( \
                        aF[ks][mf], bF[ks][sub], acc[mf][(GG) * 2 + sub], 0, 0, 0);  \
        __builtin_amdgcn_s_setprio(0);                                               \
    } while (0)

#define GP_READ_A_B0()                                                               \
    do {                                                                             \
        _Pragma("unroll")                                                            \
        for (int ks = 0; ks < 2; ++ks) {                                             \
            _Pragma("unroll")                                                        \
            for (int mf = 0; mf < 2; ++mf)                                           \
                aF[ks][mf] = *(const short8*)&lds[rA[mf] + ks * 4096];               \
            _Pragma("unroll")                                                        \
            for (int sub = 0; sub < 2; ++sub)                                        \
                bF[ks][sub] = *(const short8*)&lds[8192 + ks * 2048 + rB[sub]];      \
        }                                                                            \
    } while (0)

#define GP_READ_B(GG)                                                                \
    do {                                                                             \
        _Pragma("unroll")                                                            \
        for (int ks = 0; ks < 2; ++ks)                                               \
            _Pragma("unroll")                                                        \
            for (int sub = 0; sub < 2; ++sub)                                        \
                bF[ks][sub] = *(const short8*)&lds[8192 + (GG) * 4096 + ks * 2048 + rB[sub]]; \
    } while (0)

    // prologue: stage A(0), B0..B3(0)  (B4(0) staged inside t=0 P0)
    GP_STG_A(0);
    GP_STG_B(0, 0); GP_STG_B(0, 1); GP_STG_B(0, 2); GP_STG_B(0, 3);

    short8 aF[2][2], bF[2][2];
    for (int t = 0; t < 31; ++t) {
        // P0: A + gate0
        GP_WAIT(3);
        GP_READ_A_B0();
        GP_STG_B(t, 4);
        GP_MFMA(0);
        // P1: gate1
        GP_WAIT(3);
        GP_READ_B(1);
        GP_STG_A(t + 1);
        GP_MFMA(1);
        // P2: gate2
        GP_WAIT(4);
        GP_READ_B(2);
        GP_STG_B(t + 1, 0);
        GP_MFMA(2);
        // P3: gate3
        GP_WAIT(4);
        GP_READ_B(3);
        GP_STG_B(t + 1, 1);
        GP_MFMA(3);
        // P4: gate4
        GP_WAIT(4);
        GP_READ_B(4);
        GP_STG_B(t + 1, 2);
        GP_STG_B(t + 1, 3);
        GP_MFMA(4);
    }
    // ---- peeled last tile (t = 31): drain 3/3/2/1/0, only B4 staged ----
    GP_WAIT(3);
    GP_READ_A_B0();
    GP_STG_B(31, 4);
    GP_MFMA(0);
    GP_WAIT(3);
    GP_READ_B(1);
    GP_MFMA(1);
    GP_WAIT(2);
    GP_READ_B(2);
    GP_MFMA(2);
    GP_WAIT(1);
    GP_READ_B(3);
    GP_MFMA(3);
    GP_WAIT(0);
    GP_READ_B(4);
    GP_MFMA(4);

#undef GP_STG_A
#undef GP_STG_B
#undef GP_MFMA
#undef GP_READ_A_B0
#undef GP_READ_B

    // ---- fused epilogue: LSTM gate math straight from acc ----
    float bI[2], bO[2], bC[2], bL[2], bR[2];
    int dsub[2];
#pragma unroll
    for (int sub = 0; sub < 2; ++sub) {
        int dd = d0 + wd * 32 + sub * 16 + (lane & 15);
        dsub[sub] = dd;
        bI[sub] = bio[dd]; bO[sub] = bio[1024 + dd]; bC[sub] = bio[2048 + dd];
        bL[sub] = bfl[dd]; bR[sub] = bfr[dd];
    }
    int pmask = (1 << lp) - 1;
    int has_c = (c_in != nullptr);
#pragma unroll
    for (int mf = 0; mf < 2; ++mf) {
#pragma unroll
        for (int rr = 0; rr < 4; ++rr) {
            int row = wm * 32 + mf * 16 + (lane >> 4) * 4 + rr;
            long J = rowTile + row;
            int b = (int)(J >> lp), p = (int)(J & pmask);
            long ho = ((long)b * 255 + level_off + p) * H;
#pragma unroll
            for (int sub = 0; sub < 2; ++sub) {
                int dd = dsub[sub];
                float i_  = acc[mf][0 + sub][rr] + bI[sub];
                float o_  = acc[mf][2 + sub][rr] + bO[sub];
                float ck_ = acc[mf][4 + sub][rr] + bC[sub];
                float cv = sigf(i_) * tanh_(ck_);
                if (has_c) {
                    float fl_ = sigf(acc[mf][6 + sub][rr] + bL[sub]);
                    float fr_ = sigf(acc[mf][8 + sub][rr] + bR[sub]);
                    float cl, cr;
                    if (c_bf16) {
                        cl = bf2f(__builtin_nontemporal_load(
                                 (const u16*)c_in + (2 * J) * H + dd));
                        cr = bf2f(__builtin_nontemporal_load(
                                 (const u16*)c_in + (2 * J + 1) * H + dd));
                    } else {
                        cl = __builtin_nontemporal_load(
                                 (const float*)c_in + (2 * J) * H + dd);
                        cr = __builtin_nontemporal_load(
                                 (const float*)c_in + (2 * J + 1) * H + dd);
                    }
                    cv += fl_ * cl + fr_ * cr;
                }
                float hv = sigf(o_) * tanh_(cv);
                __builtin_nontemporal_store(hv, &outF[ho + dd]);
                if (c_bf16)
                    __builtin_nontemporal_store(f2bf(cv), (u16*)c_out + J * H + dd);
                else
                    __builtin_nontemporal_store(cv, (float*)c_out + J * H + dd);
                __builtin_nontemporal_store(f2bf(hv), hnext + J * H + dd);
            }
        }
    }
}

// ==== SPLIT-K fused partial GEMM for small levels (m <= 1024) ================
__global__ __launch_bounds__(512, 2) void gemmS(const u16* __restrict__ A,
                                                const u16* __restrict__ BT,
                                                float* __restrict__ P,
                                                int RT, int KS, int NT,
                                                int mLim, int mPad) {
    constexpr int ABASE = 8192;                 // u16
    constexpr int BUFU  = 28672;                // u16 per buffer (57,344 B)
    __shared__ __align__(16) u16 lds[2 * BUFU];
    const int tid  = threadIdx.x;
    const int lane = tid & 63;
    const int w    = tid >> 6;
    const int wm   = w >> 1;    // 0..3
    const int wd   = w & 1;     // 0..1

    int nwg = RT * 16 * KS;
    int f = blockIdx.x;
    int q = nwg >> 3, r = nwg & 7;
    int xcd = f & 7, rank = f >> 3;
    int wg = (xcd < r ? xcd * (q + 1) : r * (q + 1) + (xcd - r) * q) + rank;
    int bx  = wg % RT;
    int by  = (wg / RT) % 16;
    int ksx = wg / (RT * 16);
    long rowTile = (long)bx * 128;
    int d0 = by * 64;
    int kOff = ksx * (NT * 64);

    const u16* srcA[2];
    {
        int rr_ = w * 16 + (lane >> 2);
        int ck_ = ((lane & 3) ^ SWZ2(rr_)) * 8;
#pragma unroll
        for (int c = 0; c < 2; ++c)
            srcA[c] = A + (rowTile + rr_) * (long)K2 + kOff + c * 32 + ck_;
    }
    const u16* srcB[5];
    {
        int sr_ = (w >> 1) * 16 + (lane >> 2);
        int ck_ = ((lane & 3) ^ SWZ2(sr_)) * 8;
#pragma unroll
        for (int g = 0; g < 5; ++g)
            srcB[g] = BT + (long)(g * 1024 + d0 + sr_) * K2 + kOff + (w & 1) * 32 + ck_;
    }

    const int qv = lane >> 4;
    int rA[2];
#pragma unroll
    for (int mf = 0; mf < 2; ++mf) {
        int rl = wm * 32 + mf * 16 + (lane & 15);           // 0..127
        rA[mf] = rl * 32 + ((qv ^ SWZ2(rl)) * 8);
    }
    int rB[2];
#pragma unroll
    for (int sub = 0; sub < 2; ++sub) {
        int rb = wd * 32 + sub * 16 + (lane & 15);
        rB[sub] = rb * 32 + ((qv ^ SWZ2(rb)) * 8);
    }

    floatx4 acc[2][10];
#pragma unroll
    for (int mf = 0; mf < 2; ++mf)
#pragma unroll
        for (int nf = 0; nf < 10; ++nf)
            acc[mf][nf] = (floatx4){0.f, 0.f, 0.f, 0.f};

#define GS_STAGE(TT, DD)                                                             \
    do {                                                                             \
        _Pragma("unroll")                                                            \
        for (int c = 0; c < 2; ++c)                                                  \
            __builtin_amdgcn_global_load_lds(                                        \
                (const __attribute__((address_space(1))) void*)(srcA[c] + (TT) * 64),\
                (__attribute__((address_space(3))) void*)(lds + (DD) * BUFU + c * 4096 + tid * 8), 16, 0, 0); \
        _Pragma("unroll")                                                            \
        for (int g = 0; g < 5; ++g)                                                  \
            __builtin_amdgcn_global_load_lds(                                        \
                (const __attribute__((address_space(1))) void*)(srcB[g] + (TT) * 64),\
                (__attribute__((address_space(3))) void*)(lds + (DD) * BUFU + ABASE + g * 4096 + (w & 1) * 2048 + (w >> 1) * 512 + lane * 8), 16, 0, 0); \
    } while (0)

    GS_STAGE(0, 0);

    for (int t = 0; t < NT; ++t) {
        int d = t & 1;
        asm volatile("s_barrier" ::: "memory");
        if (t < NT - 1) {
            GS_STAGE(t + 1, d ^ 1);
            asm volatile("s_waitcnt vmcnt(7)" ::: "memory");
        } else {
            asm volatile("s_waitcnt vmcnt(0)" ::: "memory");
        }
        asm volatile("s_barrier" ::: "memory");
        const u16* bufD = lds + d * BUFU;
#pragma unroll
        for (int ks = 0; ks < 2; ++ks) {
            short8 aF[2];
#pragma unroll
            for (int mf = 0; mf < 2; ++mf)
                aF[mf] = *(const short8*)&bufD[rA[mf] + ks * 4096];
#pragma unroll
            for (int g = 0; g < 5; ++g) {
                short8 bF[2];
#pragma unroll
                for (int sub = 0; sub < 2; ++sub)
                    bF[sub] = *(const short8*)&bufD[ABASE + g * 4096 + ks * 2048 + rB[sub]];
                __builtin_amdgcn_s_setprio(1);
#pragma unroll
                for (int mf = 0; mf < 2; ++mf)
#pragma unroll
                    for (int sub = 0; sub < 2; ++sub)
                        acc[mf][g * 2 + sub] = __builtin_amdgcn_mfma_f32_16x16x32_bf16(
                            aF[mf], bF[sub], acc[mf][g * 2 + sub], 0, 0, 0);
                __builtin_amdgcn_s_setprio(0);
            }
        }
    }
#undef GS_STAGE

    int dsub[2];
#pragma unroll
    for (int sub = 0; sub < 2; ++sub)
        dsub[sub] = d0 + wd * 32 + sub * 16 + (lane & 15);
#pragma unroll
    for (int mf = 0; mf < 2; ++mf) {
#pragma unroll
        for (int rr = 0; rr < 4; ++rr) {
            int row = wm * 32 + mf * 16 + (lane >> 4) * 4 + rr;
            long J = rowTile + row;
            if (J < mLim) {
                long pb = ((long)ksx * mPad + J) * NTOT;
#pragma unroll
                for (int g = 0; g < 5; ++g)
#pragma unroll
                    for (int sub = 0; sub < 2; ++sub)
                        P[pb + g * 1024 + dsub[sub]] = acc[mf][g * 2 + sub][rr];
            }
        }
    }
}

// ---- reduce split-K partials + gate math ----
__global__ void redgate(const float* __restrict__ P, const float* __restrict__ bio,
                        const float* __restrict__ bfl, const float* __restrict__ bfr,
                        const void* __restrict__ c_in, void* __restrict__ c_out, int c_bf16,
                        float* __restrict__ outF, u16* __restrict__ hnext,
                        int lp, int level_off, int mc, int KS, int mPad) {
    int idx = blockIdx.x * 256 + threadIdx.x;
    int j = idx >> 8;
    if (j >= mc) return;
    int d = (idx & 255) * 4;
    int b = j >> lp, p = j & ((1 << lp) - 1);
    float ac[5][4] = {};
    for (int s = 0; s < KS; ++s) {
        long pb = ((long)s * mPad + j) * NTOT + d;
#pragma unroll
        for (int g = 0; g < 5; ++g) {
            float4 v = *(const float4*)&P[pb + g * 1024];
            ac[g][0] += v.x; ac[g][1] += v.y; ac[g][2] += v.z; ac[g][3] += v.w;
        }
    }
    float4 bi = *(const float4*)&bio[d];
    float4 bo = *(const float4*)&bio[1024 + d];
    float4 bc = *(const float4*)&bio[2048 + d];
    float4 bl = *(const float4*)&bfl[d];
    float4 br = *(const float4*)&bfr[d];
    const float* fbi = (const float*)&bi; const float* fbo = (const float*)&bo;
    const float* fbc = (const float*)&bc; const float* fbl = (const float*)&bl;
    const float* fbr = (const float*)&br;
    float clv[4], crv[4];
    {
        long cb = ((long)b * (2 << lp) + 2 * p) * H + d;
        if (c_bf16) {
            uint2 ul = *(const uint2*)((const u16*)c_in + cb);
            uint2 ur = *(const uint2*)((const u16*)c_in + cb + H);
            clv[0] = bf2f((u16)ul.x); clv[1] = bf2f((u16)(ul.x >> 16));
            clv[2] = bf2f((u16)ul.y); clv[3] = bf2f((u16)(ul.y >> 16));
            crv[0] = bf2f((u16)ur.x); crv[1] = bf2f((u16)(ur.x >> 16));
            crv[2] = bf2f((u16)ur.y); crv[3] = bf2f((u16)(ur.y >> 16));
        } else {
            float4 l4 = *(const float4*)((const float*)c_in + cb);
            float4 r4 = *(const float4*)((const float*)c_in + cb + H);
            clv[0] = l4.x; clv[1] = l4.y; clv[2] = l4.z; clv[3] = l4.w;
            crv[0] = r4.x; crv[1] = r4.y; crv[2] = r4.z; crv[3] = r4.w;
        }
    }
    float cv[4], hv[4];
#pragma unroll
    for (int qq = 0; qq < 4; ++qq) {
        float c = sigf(ac[0][qq] + fbi[qq]) * tanh_(ac[2][qq] + fbc[qq]);
        c += sigf(ac[3][qq] + fbl[qq]) * clv[qq] + sigf(ac[4][qq] + fbr[qq]) * crv[qq];
        cv[qq] = c;
        hv[qq] = sigf(ac[1][qq] + fbo[qq]) * tanh_(c);
    }
    long co = (long)j * H + d;
    if (c_bf16) {
        uint2 oc; oc.x = pk2(cv[0], cv[1]); oc.y = pk2(cv[2], cv[3]);
        *(uint2*)((u16*)c_out + co) = oc;
    } else {
        *(float4*)((float*)c_out + co) = make_float4(cv[0], cv[1], cv[2], cv[3]);
    }
    long oi = ((long)b * 255 + level_off + p) * H + d;
    *(float4*)&outF[oi] = make_float4(hv[0], hv[1], hv[2], hv[3]);
    uint2 oh; oh.x = pk2(hv[0], hv[1]); oh.y = pk2(hv[2], hv[3]);
    *(uint2*)(hnext + (long)j * H + d) = oh;
}

// ---- gates (legacy fallback path) ----
__global__ void gates(const float* __restrict__ G, const float* __restrict__ bio,
                      const float* __restrict__ bfl, const float* __restrict__ bfr,
                      const void* __restrict__ c_in, void* __restrict__ c_out, int c_bf16,
                      float* __restrict__ outF, u16* __restrict__ hnext,
                      int lp, int level_off, int row0, int mc) {
    int idx = blockIdx.x * 256 + threadIdx.x;
    int j = idx >> 8;
    if (j >= mc) return;
    int d = (idx & 255) * 4;
    int J = row0 + j;
    int b = J >> lp, p = J & ((1 << lp) - 1);
    long gb = (long)j * NTOT;
    float4 gi = *(const float4*)&G[gb + d];
    float4 go = *(const float4*)&G[gb + 1024 + d];
    float4 gc = *(const float4*)&G[gb + 2048 + d];
    float4 gl = *(const float4*)&G[gb + 3072 + d];
    float4 gr = *(const float4*)&G[gb + 4096 + d];
    float4 bi = *(const float4*)&bio[d];
    float4 bo = *(const float4*)&bio[1024 + d];
    float4 bc = *(const float4*)&bio[2048 + d];
    float4 bl = *(const float4*)&bfl[d];
    float4 br = *(const float4*)&bfr[d];
    float clv[4] = {0.f, 0.f, 0.f, 0.f}, crv[4] = {0.f, 0.f, 0.f, 0.f};
    if (c_in) {
        long cb = ((long)b * (2 << lp) + 2 * p) * H + d;
        if (c_bf16) {
            uint2 ul = *(const uint2*)((const u16*)c_in + cb);
            uint2 ur = *(const uint2*)((const u16*)c_in + cb + H);
            clv[0] = bf2f((u16)ul.x); clv[1] = bf2f((u16)(ul.x >> 16));
            clv[2] = bf2f((u16)ul.y); clv[3] = bf2f((u16)(ul.y >> 16));
            crv[0] = bf2f((u16)ur.x); crv[1] = bf2f((u16)(ur.x >> 16));
            crv[2] = bf2f((u16)ur.y); crv[3] = bf2f((u16)(ur.y >> 16));
        } else {
            float4 l4 = *(const float4*)((const float*)c_in + cb);
            float4 r4 = *(const float4*)((const float*)c_in + cb + H);
            clv[0] = l4.x; clv[1] = l4.y; clv[2] = l4.z; clv[3] = l4.w;
            crv[0] = r4.x; crv[1] = r4.y; crv[2] = r4.z; crv[3] = r4.w;
        }
    }
    const float* fgi = (const float*)&gi; const float* fgo = (const float*)&go;
    const float* fgc = (const float*)&gc; const float* fgl = (const float*)&gl;
    const float* fgr = (const float*)&gr;
    const float* fbi = (const float*)&bi; const float* fbo = (const float*)&bo;
    const float* fbc = (const float*)&bc; const float* fbl = (const float*)&bl;
    const float* fbr = (const float*)&br;
    float cv[4], hv[4];
    int has_c = (c_in != nullptr);
#pragma unroll
    for (int qq = 0; qq < 4; ++qq) {
        float c = sigf(fgi[qq] + fbi[qq]) * tanh_(fgc[qq] + fbc[qq]);
        if (has_c)
            c += sigf(fgl[qq] + fbl[qq]) * clv[qq] + sigf(fgr[qq] + fbr[qq]) * crv[qq];
        cv[qq] = c;
        hv[qq] = sigf(fgo[qq] + fbo[qq]) * tanh_(c);
    }
    long co = (long)J * H + d;
    if (c_bf16) {
        uint2 oc; oc.x = pk2(cv[0], cv[1]); oc.y = pk2(cv[2], cv[3]);
        *(uint2*)((u16*)c_out + co) = oc;
    } else {
        *(float4*)((float*)c_out + co) = make_float4(cv[0], cv[1], cv[2], cv[3]);
    }
    long oi = ((long)b * 255 + level_off + p) * H + d;
    *(float4*)&outF[oi] = make_float4(hv[0], hv[1], hv[2], hv[3]);
    uint2 oh; oh.x = pk2(hv[0], hv[1]); oh.y = pk2(hv[2], hv[3]);
    *(uint2*)(hnext + (long)J * H + d) = oh;
}

__global__ void root_copy(const float* __restrict__ outF, const void* __restrict__ c_root,
                          int c_bf16, float* __restrict__ tail) {
    int idx = blockIdx.x * 256 + threadIdx.x;   // 131072
    if (idx < 65536) {
        int b = idx >> 10, d = idx & 1023;
        tail[idx] = outF[((long)b * 255 + 254) * H + d];
    } else {
        int i2 = idx - 65536;
        tail[idx] = c_bf16 ? bf2f(((const u16*)c_root)[i2]) : ((const float*)c_root)[i2];
    }
}

extern "C" void kernel_launch(void* const* d_in, const int* in_sizes, int n_in,
                              void* d_out, int out_size, void* d_ws, size_t ws_size,
                              hipStream_t stream) {
    const int* tokens = (const int*)d_in[0];
    const float* emb = (const float*)d_in[1];
    const float* Wio = (const float*)d_in[2];
    const float* bio = (const float*)d_in[3];
    const float* Uio = (const float*)d_in[4];
    const float* Wfl = (const float*)d_in[5];
    const float* bfl = (const float*)d_in[6];
    const float* Ufl = (const float*)d_in[7];
    const float* Wfr = (const float*)d_in[8];
    const float* bfr = (const float*)d_in[9];
    const float* Ufr = (const float*)d_in[10];
    float* outF = (float*)d_out;

    // ---- ws carve (adaptive) ----
    char* ws = (char*)d_ws;
    size_t off = 0;
    u16* WT   = (u16*)(ws + off); off += (size_t)NTOT * K2 * 2;        // 20.97 MB
    u16* leaf = (u16*)(ws + off); off += (size_t)BATCH * 256 * H * 2;  // 33.55 MB
    u16* hE   = (u16*)(ws + off); off += (size_t)8192 * H * 2;         // 16.78 MB
    u16* hO   = (u16*)(ws + off); off += (size_t)4096 * H * 2;         //  8.39 MB
    size_t cEf = (size_t)8192 * H, cOf = (size_t)4096 * H;             // elements
    int c_bf16 = (ws_size >= off + (cEf + cOf) * 4 + (size_t)512 * NTOT * 4) ? 0 : 1;
    size_t csz = c_bf16 ? 2 : 4;
    void* cE = (void*)(ws + off); off += cEf * csz;
    void* cO = (void*)(ws + off); off += cOf * csz;
    size_t avail = (ws_size > off) ? (ws_size - off) : 0;
    // split-K partial buffer: 2048 rows x 5120 fp32 = 41.9 MB (overlaps legacy G)
    size_t Pbytes = (size_t)2048 * NTOT * 4;
    int splitOK = (avail >= Pbytes);
    float* P = (float*)(ws + off);
    long Grows = (long)(avail / ((size_t)NTOT * 4));
    if (Grows > 512) Grows = 512;           // legacy path only handles m <= 512
    Grows &= ~127L;
    if (Grows < 128) Grows = 128;
    float* G = (float*)(ws + off);

    pack_weights<<<dim3(64, 160), 256, 0, stream>>>(Wio, Uio, Wfl, Ufl, Wfr, Ufr, WT);
    leaf_pack<<<16384, 256, 0, stream>>>(tokens, emb, leaf);

    const int off_out[8] = {0, 128, 192, 224, 240, 248, 252, 254};
    for (int li = 0; li < 8; ++li) {
        int lp = 7 - li;
        long m = (long)BATCH << lp;
        const u16* Acur = (li == 0) ? leaf : ((li & 1) ? hE : hO);
        u16* hnext = (li & 1) ? hO : hE;
        const void* c_in = (li == 0) ? nullptr : ((li & 1) ? cE : cO);
        void* c_out = (li & 1) ? cO : cE;
        if (m >= 2048) {
            int gm = (int)(m >> 7);
            gemmP128<<<gm * 16, 512, 0, stream>>>(Acur, WT, bio, bfl, bfr,
                                                  c_in, c_out, c_bf16, outF, hnext,
                                                  lp, off_out[li], gm);
        } else if (splitOK) {
            int KS = (m == 1024) ? 2 : (m == 512) ? 4 : (m == 256) ? 8 : 16;
            int RT = (m >= 128) ? (int)(m >> 7) : 1;
            int mPad = RT * 128;
            int NT = 32 / KS;
            gemmS<<<RT * 16 * KS, 512, 0, stream>>>(Acur, WT, P, RT, KS, NT,
                                                    (int)m, mPad);
            redgate<<<(int)m, 256, 0, stream>>>(P, bio, bfl, bfr, c_in, c_out, c_bf16,
                                                outF, hnext, lp, off_out[li],
                                                (int)m, KS, mPad);
        } else {
            for (long row0 = 0; row0 < m; row0 += Grows) {
                int mc = (int)((m - row0 > Grows) ? Grows : (m - row0));
                dim3 grid((mc + BM - 1) / BM, NTOT / BN);
                gemm_bt<<<grid, 256, 0, stream>>>(Acur + row0 * K2, WT, G, mc);
                gates<<<mc, 256, 0, stream>>>(G, bio, bfl, bfr, c_in, c_out, c_bf16,
                                              outF, hnext, lp, off_out[li], (int)row0, mc);
            }
        }
    }
    root_copy<<<512, 256, 0, stream>>>(outF, cO, c_bf16, outF + (size_t)BATCH * 255 * H);
}

// Round 11
// 666.611 us; speedup vs baseline: 1.0116x; 1.0116x over previous
//
#include <hip/hip_runtime.h>
#include <stdint.h>

#define H     1024
#define K2    2048
#define NTOT  5120
#define BATCH 64
#define BM 128
#define BN 128
#define BK 64

typedef unsigned short u16;
typedef __attribute__((ext_vector_type(8))) short short8;
typedef __attribute__((ext_vector_type(4))) float floatx4;

__device__ __forceinline__ float bf2f(u16 u) {
    return __uint_as_float(((uint32_t)u) << 16);
}
__device__ __forceinline__ u16 f2bf(float f) {
    uint32_t u = __float_as_uint(f);
    u += 0x7fffu + ((u >> 16) & 1u);
    return (u16)(u >> 16);
}
__device__ __forceinline__ uint32_t pk2(float lo, float hi) {
    return (uint32_t)f2bf(lo) | ((uint32_t)f2bf(hi) << 16);
}
__device__ __forceinline__ float sigf(float x) {
    return 1.0f / (1.0f + __expf(-x));
}
__device__ __forceinline__ float tanh_(float x) {
    float e = __expf(-2.0f * fabsf(x));
    float r = (1.0f - e) / (1.0f + e);
    return copysignf(r, x);
}

// ---- fused pre-work: blocks [0,10240) pack weights, rest gather leaves ----
// pack: fp32 W/U -> bf16 WT[n][k] (k<1024 from W, else U), 32x32 transpose tiles.
// leaf: leaf[node][d] = bf16(emb[tokens[node]][d]).  Independent kernels fused
// into ONE dispatch so the two memory-bound streams overlap.
__global__ void fuse_pre(const float* __restrict__ Wio, const float* __restrict__ Uio,
                         const float* __restrict__ Wfl, const float* __restrict__ Ufl,
                         const float* __restrict__ Wfr, const float* __restrict__ Ufr,
                         u16* __restrict__ WT,
                         const int* __restrict__ tokens, const float* __restrict__ emb,
                         u16* __restrict__ leaf) {
    __shared__ u16 tile[32][33];
    int blk = blockIdx.x;
    int t = threadIdx.x;
    if (blk < 10240) {
        int k0 = (blk & 63) * 32;
        int n0 = (blk >> 6) * 32;
        const float *Wp, *Up; int ncols, nloc;
        if (n0 < 3072)      { Wp = Wio; Up = Uio; ncols = 3072; nloc = n0; }
        else if (n0 < 4096) { Wp = Wfl; Up = Ufl; ncols = 1024; nloc = n0 - 3072; }
        else                { Wp = Wfr; Up = Ufr; ncols = 1024; nloc = n0 - 4096; }
        int c = t & 31, r = t >> 5;
#pragma unroll
        for (int i = 0; i < 4; ++i) {
            int rr = r + i * 8;
            int k = k0 + rr;
            float v = (k < 1024) ? Wp[(long)k * ncols + nloc + c]
                                 : Up[(long)(k - 1024) * ncols + nloc + c];
            tile[rr][c] = f2bf(v);
        }
        __syncthreads();
#pragma unroll
        for (int i = 0; i < 4; ++i) {
            int rr = r + i * 8;
            WT[(long)(n0 + rr) * K2 + k0 + c] = tile[c][rr];
        }
    } else {
        int idx = (blk - 10240) * 256 + t;      // 16384 blocks -> 4,194,304 float4
        int node = idx >> 8;
        int d4 = idx & 255;
        int tok = tokens[node];
        float4 v = ((const float4*)emb)[(long)tok * 256 + d4];
        uint2 o; o.x = pk2(v.x, v.y); o.y = pk2(v.z, v.w);
        ((uint2*)leaf)[(long)node * 256 + d4] = o;
    }
}

// ---- GEMM (m97 structure, 128x128) legacy fallback ----
__global__ void gemm_bt(const u16* __restrict__ A, const u16* __restrict__ BT,
                        float* __restrict__ G, int mc) {
    __shared__ __align__(16) u16 AsBs[16896];   // 33,792 B; K-loop: As|Bs, epilogue: epi
    u16* As = AsBs;
    u16* Bs = AsBs + 8192;
    float* epi = (float*)AsBs;                  // 64 x 132 fp32
    int tid  = threadIdx.x;
    int lane = tid & 63;
    int w    = tid >> 6;
    int wm   = w >> 1, wn = w & 1;
    int rowTile = blockIdx.x * BM;
    int n0      = blockIdx.y * BN;

    const u16* asrc[4];
    const u16* bsrc[4];
#pragma unroll
    for (int cc = 0; cc < 4; ++cc) {
        int r = cc * 32 + w * 8 + (lane >> 3);
        int j = rowTile + r; if (j >= mc) j = mc - 1;
        asrc[cc] = A + (long)j * K2 + (lane & 7) * 8;
        bsrc[cc] = BT + (long)(n0 + r) * K2 + (lane & 7) * 8;
    }

    floatx4 acc[4][4];
#pragma unroll
    for (int mt = 0; mt < 4; ++mt)
#pragma unroll
        for (int nt = 0; nt < 4; ++nt)
            acc[mt][nt] = (floatx4){0.f, 0.f, 0.f, 0.f};

    for (int k0 = 0; k0 < K2; k0 += BK) {
#pragma unroll
        for (int cc = 0; cc < 4; ++cc) {
            __builtin_amdgcn_global_load_lds(
                (const __attribute__((address_space(1))) void*)(asrc[cc] + k0),
                (__attribute__((address_space(3))) void*)(As + cc * 2048 + w * 512), 16, 0, 0);
            __builtin_amdgcn_global_load_lds(
                (const __attribute__((address_space(1))) void*)(bsrc[cc] + k0),
                (__attribute__((address_space(3))) void*)(Bs + cc * 2048 + w * 512), 16, 0, 0);
        }
        __syncthreads();
#pragma unroll
        for (int kb = 0; kb < 2; ++kb) {
            int kfo = kb * 32 + (lane >> 4) * 8;
            short8 af[4], bfv[4];
#pragma unroll
            for (int mt = 0; mt < 4; ++mt)
                af[mt] = *(const short8*)&As[(wm * 64 + mt * 16 + (lane & 15)) * BK + kfo];
#pragma unroll
            for (int nt = 0; nt < 4; ++nt)
                bfv[nt] = *(const short8*)&Bs[(wn * 64 + nt * 16 + (lane & 15)) * BK + kfo];
#pragma unroll
            for (int mt = 0; mt < 4; ++mt)
#pragma unroll
                for (int nt = 0; nt < 4; ++nt)
                    acc[mt][nt] = __builtin_amdgcn_mfma_f32_16x16x32_bf16(
                        af[mt], bfv[nt], acc[mt][nt], 0, 0, 0);
        }
        __syncthreads();
    }

#pragma unroll
    for (int s = 0; s < 2; ++s) {
        if (wm == s) {
#pragma unroll
            for (int mt = 0; mt < 4; ++mt)
#pragma unroll
                for (int r = 0; r < 4; ++r) {
                    int lrow = mt * 16 + (lane >> 4) * 4 + r;
#pragma unroll
                    for (int nt = 0; nt < 4; ++nt)
                        epi[lrow * 132 + wn * 64 + nt * 16 + (lane & 15)] = acc[mt][nt][r];
                }
        }
        __syncthreads();
        int gr0 = rowTile + s * 64;
#pragma unroll
        for (int k = 0; k < 8; ++k) {
            int f4 = tid + k * 256;     // 0..2047 float4 slots = 64 rows x 32
            int row = f4 >> 5, c4 = f4 & 31;
            if (gr0 + row < mc) {
                float4 v = *(const float4*)&epi[row * 132 + c4 * 4];
                *(float4*)&G[(long)(gr0 + row) * NTOT + n0 + c4 * 4] = v;
            }
        }
        __syncthreads();
    }
}

// ==== FUSED 128x64-d GEMM+gates, single-buffer 5-phase, 2 blocks/CU ==========
// (unchanged from the passing round-10 kernel)
#define SWZ2(r) (((r) >> 1) & 3)

#define GP_WAIT(VM)                                                                  \
    asm volatile("s_waitcnt vmcnt(" #VM ") lgkmcnt(0)\n\ts_barrier" ::: "memory")

__global__ __launch_bounds__(512, 4) void gemmP128(const u16* __restrict__ A,
                                                   const u16* __restrict__ BT,
                                                   const float* __restrict__ bio,
                                                   const float* __restrict__ bfl,
                                                   const float* __restrict__ bfr,
                                                   const void* __restrict__ c_in,
                                                   void* __restrict__ c_out, int c_bf16,
                                                   float* __restrict__ outF,
                                                   u16* __restrict__ hnext,
                                                   int lp, int level_off, int gm) {
    __shared__ __align__(16) u16 lds[28672];    // 56 KiB: A [ks:2]8KB | B [g:5][ks:2]4KB
    const int tid  = threadIdx.x;
    const int lane = tid & 63;
    const int w    = tid >> 6;
    const int wm   = w >> 1;    // 0..3
    const int wd   = w & 1;     // 0..1

    int f = blockIdx.x;
    int xcd = f & 7, c = f >> 3;
    int by = (xcd & 1) * 8 + (c & 7);            // d-tile 0..15
    int bx = (xcd >> 1) * (gm >> 2) + (c >> 3);  // row-tile 0..gm-1
    long rowTile = (long)bx * 128;
    int d0 = by * 64;

    const u16* srcA[2];
    {
        int rr_ = w * 16 + (lane >> 2);
        int ck_ = ((lane & 3) ^ SWZ2(rr_)) * 8;
#pragma unroll
        for (int cc = 0; cc < 2; ++cc)
            srcA[cc] = A + (rowTile + rr_) * (long)K2 + cc * 32 + ck_;
    }
    const u16* srcB[5];
    {
        int sr_ = (w >> 1) * 16 + (lane >> 2);
        int ck_ = ((lane & 3) ^ SWZ2(sr_)) * 8;
#pragma unroll
        for (int g = 0; g < 5; ++g)
            srcB[g] = BT + (long)(g * 1024 + d0 + sr_) * K2 + (w & 1) * 32 + ck_;
    }

    const int qv = lane >> 4;
    int rA[2];
#pragma unroll
    for (int mf = 0; mf < 2; ++mf) {
        int rg = wm * 32 + mf * 16 + (lane & 15);           // 0..127
        rA[mf] = rg * 32 + ((qv ^ SWZ2(rg)) * 8);
    }
    int rB[2];
#pragma unroll
    for (int sub = 0; sub < 2; ++sub) {
        int rb = wd * 32 + sub * 16 + (lane & 15);          // row in 64-row strip
        rB[sub] = rb * 32 + ((qv ^ SWZ2(rb)) * 8);
    }

    floatx4 acc[2][10];
#pragma unroll
    for (int mf = 0; mf < 2; ++mf)
#pragma unroll
        for (int nf = 0; nf < 10; ++nf)
            acc[mf][nf] = (floatx4){0.f, 0.f, 0.f, 0.f};

#define GP_STG_A(TT)                                                                 \
    do {                                                                             \
        _Pragma("unroll")                                                            \
        for (int cc = 0; cc < 2; ++cc)                                               \
            __builtin_amdgcn_global_load_lds(                                        \
                (const __attribute__((address_space(1))) void*)(srcA[cc] + (TT) * 64),\
                (__attribute__((address_space(3))) void*)(lds + cc * 4096 + tid * 8), 16, 0, 0); \
    } while (0)

#define GP_STG_B(TT, GG)                                                             \
    __builtin_amdgcn_global_load_lds(                                                \
        (const __attribute__((address_space(1))) void*)(srcB[GG] + (TT) * 64),       \
        (__attribute__((address_space(3))) void*)(lds + 8192 + (GG) * 4096 + (w & 1) * 2048 + (w >> 1) * 512 + lane * 8), 16, 0, 0)

#define GP_MFMA(GG)                                                                  \
    do {                                                                             \
        __builtin_amdgcn_s_setprio(1);                                               \
        _Pragma("unroll")                                                            \
        for (int ks = 0; ks < 2; ++ks)                                               \
            _Pragma("unroll")                                                        \
            for (int mf = 0; mf < 2; ++mf)                                           \
                _Pragma("unroll")                                                    \
                for (int sub = 0; sub < 2; ++sub)                                    \
                    acc[mf][(GG) * 2 + sub] = __builtin_amdgcn_mfma_f32_16x16x32_bf16( \
                        aF[ks][mf], bF[ks][sub], acc[mf][(GG) * 2 + sub], 0, 0, 0);  \
        __builtin_amdgcn_s_setprio(0);                                               \
    } while (0)

#define GP_READ_A_B0()                                                               \
    do {                                                                             \
        _Pragma("unroll")                                                            \
        for (int ks = 0; ks < 2; ++ks) {                                             \
            _Pragma("unroll")                                                        \
            for (int mf = 0; mf < 2; ++mf)                                           \
                aF[ks][mf] = *(const short8*)&lds[rA[mf] + ks * 4096];               \
            _Pragma("unroll")                                                        \
            for (int sub = 0; sub < 2; ++sub)                                        \
                bF[ks][sub] = *(const short8*)&lds[8192 + ks * 2048 + rB[sub]];      \
        }                                                                            \
    } while (0)

#define GP_READ_B(GG)                                                                \
    do {                                                                             \
        _Pragma("unroll")                                                            \
        for (int ks = 0; ks < 2; ++ks)                                               \
            _Pragma("unroll")                                                        \
            for (int sub = 0; sub < 2; ++sub)                                        \
                bF[ks][sub] = *(const short8*)&lds[8192 + (GG) * 4096 + ks * 2048 + rB[sub]]; \
    } while (0)

    // prologue: stage A(0), B0..B3(0)  (B4(0) staged inside t=0 P0)
    GP_STG_A(0);
    GP_STG_B(0, 0); GP_STG_B(0, 1); GP_STG_B(0, 2); GP_STG_B(0, 3);

    short8 aF[2][2], bF[2][2];
    for (int t = 0; t < 31; ++t) {
        GP_WAIT(3);
        GP_READ_A_B0();
        GP_STG_B(t, 4);
        GP_MFMA(0);
        GP_WAIT(3);
        GP_READ_B(1);
        GP_STG_A(t + 1);
        GP_MFMA(1);
        GP_WAIT(4);
        GP_READ_B(2);
        GP_STG_B(t + 1, 0);
        GP_MFMA(2);
        GP_WAIT(4);
        GP_READ_B(3);
        GP_STG_B(t + 1, 1);
        GP_MFMA(3);
        GP_WAIT(4);
        GP_READ_B(4);
        GP_STG_B(t + 1, 2);
        GP_STG_B(t + 1, 3);
        GP_MFMA(4);
    }
    GP_WAIT(3);
    GP_READ_A_B0();
    GP_STG_B(31, 4);
    GP_MFMA(0);
    GP_WAIT(3);
    GP_READ_B(1);
    GP_MFMA(1);
    GP_WAIT(2);
    GP_READ_B(2);
    GP_MFMA(2);
    GP_WAIT(1);
    GP_READ_B(3);
    GP_MFMA(3);
    GP_WAIT(0);
    GP_READ_B(4);
    GP_MFMA(4);

#undef GP_STG_A
#undef GP_STG_B
#undef GP_MFMA
#undef GP_READ_A_B0
#undef GP_READ_B

    // ---- fused epilogue: LSTM gate math straight from acc ----
    float bI[2], bO[2], bC[2], bL[2], bR[2];
    int dsub[2];
#pragma unroll
    for (int sub = 0; sub < 2; ++sub) {
        int dd = d0 + wd * 32 + sub * 16 + (lane & 15);
        dsub[sub] = dd;
        bI[sub] = bio[dd]; bO[sub] = bio[1024 + dd]; bC[sub] = bio[2048 + dd];
        bL[sub] = bfl[dd]; bR[sub] = bfr[dd];
    }
    int pmask = (1 << lp) - 1;
    int has_c = (c_in != nullptr);
#pragma unroll
    for (int mf = 0; mf < 2; ++mf) {
#pragma unroll
        for (int rr = 0; rr < 4; ++rr) {
            int row = wm * 32 + mf * 16 + (lane >> 4) * 4 + rr;
            long J = rowTile + row;
            int b = (int)(J >> lp), p = (int)(J & pmask);
            long ho = ((long)b * 255 + level_off + p) * H;
#pragma unroll
            for (int sub = 0; sub < 2; ++sub) {
                int dd = dsub[sub];
                float i_  = acc[mf][0 + sub][rr] + bI[sub];
                float o_  = acc[mf][2 + sub][rr] + bO[sub];
                float ck_ = acc[mf][4 + sub][rr] + bC[sub];
                float cv = sigf(i_) * tanh_(ck_);
                if (has_c) {
                    float fl_ = sigf(acc[mf][6 + sub][rr] + bL[sub]);
                    float fr_ = sigf(acc[mf][8 + sub][rr] + bR[sub]);
                    float cl, cr;
                    if (c_bf16) {
                        cl = bf2f(__builtin_nontemporal_load(
                                 (const u16*)c_in + (2 * J) * H + dd));
                        cr = bf2f(__builtin_nontemporal_load(
                                 (const u16*)c_in + (2 * J + 1) * H + dd));
                    } else {
                        cl = __builtin_nontemporal_load(
                                 (const float*)c_in + (2 * J) * H + dd);
                        cr = __builtin_nontemporal_load(
                                 (const float*)c_in + (2 * J + 1) * H + dd);
                    }
                    cv += fl_ * cl + fr_ * cr;
                }
                float hv = sigf(o_) * tanh_(cv);
                __builtin_nontemporal_store(hv, &outF[ho + dd]);
                if (c_bf16)
                    __builtin_nontemporal_store(f2bf(cv), (u16*)c_out + J * H + dd);
                else
                    __builtin_nontemporal_store(cv, (float*)c_out + J * H + dd);
                __builtin_nontemporal_store(f2bf(hv), hnext + J * H + dd);
            }
        }
    }
}

// ==== SPLIT-K fused partial GEMM (m <= 1024): single-buffer 5-phase =========
// Same pipeline/constants as gemmP128 (7 loads/tile; steady waits 3/3/4/4/4,
// peel 3/3/2/1/0 — valid for any NT>=1), with K offset kOff and NT tiles;
// writes RAW partials to P[(ksx*mPad + J)*NTOT + g*1024 + dd].
__global__ __launch_bounds__(512, 4) void gemmS(const u16* __restrict__ A,
                                                const u16* __restrict__ BT,
                                                float* __restrict__ P,
                                                int RT, int KS, int NT,
                                                int mLim, int mPad) {
    __shared__ __align__(16) u16 lds[28672];    // 56 KiB, single buffer
    const int tid  = threadIdx.x;
    const int lane = tid & 63;
    const int w    = tid >> 6;
    const int wm   = w >> 1;    // 0..3
    const int wd   = w & 1;     // 0..1

    int nwg = RT * 16 * KS;
    int f = blockIdx.x;
    int q = nwg >> 3, r = nwg & 7;
    int xcd = f & 7, rank = f >> 3;
    int wg = (xcd < r ? xcd * (q + 1) : r * (q + 1) + (xcd - r) * q) + rank;
    int bx  = wg % RT;
    int by  = (wg / RT) % 16;
    int ksx = wg / (RT * 16);
    long rowTile = (long)bx * 128;
    int d0 = by * 64;
    int kOff = ksx * (NT * 64);

    const u16* srcA[2];
    {
        int rr_ = w * 16 + (lane >> 2);
        int ck_ = ((lane & 3) ^ SWZ2(rr_)) * 8;
#pragma unroll
        for (int cc = 0; cc < 2; ++cc)
            srcA[cc] = A + (rowTile + rr_) * (long)K2 + kOff + cc * 32 + ck_;
    }
    const u16* srcB[5];
    {
        int sr_ = (w >> 1) * 16 + (lane >> 2);
        int ck_ = ((lane & 3) ^ SWZ2(sr_)) * 8;
#pragma unroll
        for (int g = 0; g < 5; ++g)
            srcB[g] = BT + (long)(g * 1024 + d0 + sr_) * K2 + kOff + (w & 1) * 32 + ck_;
    }

    const int qv = lane >> 4;
    int rA[2];
#pragma unroll
    for (int mf = 0; mf < 2; ++mf) {
        int rg = wm * 32 + mf * 16 + (lane & 15);           // 0..127
        rA[mf] = rg * 32 + ((qv ^ SWZ2(rg)) * 8);
    }
    int rB[2];
#pragma unroll
    for (int sub = 0; sub < 2; ++sub) {
        int rb = wd * 32 + sub * 16 + (lane & 15);
        rB[sub] = rb * 32 + ((qv ^ SWZ2(rb)) * 8);
    }

    floatx4 acc[2][10];
#pragma unroll
    for (int mf = 0; mf < 2; ++mf)
#pragma unroll
        for (int nf = 0; nf < 10; ++nf)
            acc[mf][nf] = (floatx4){0.f, 0.f, 0.f, 0.f};

#define GS_STG_A(TT)                                                                 \
    do {                                                                             \
        _Pragma("unroll")                                                            \
        for (int cc = 0; cc < 2; ++cc)                                               \
            __builtin_amdgcn_global_load_lds(                                        \
                (const __attribute__((address_space(1))) void*)(srcA[cc] + (TT) * 64),\
                (__attribute__((address_space(3))) void*)(lds + cc * 4096 + tid * 8), 16, 0, 0); \
    } while (0)

#define GS_STG_B(TT, GG)                                                             \
    __builtin_amdgcn_global_load_lds(                                                \
        (const __attribute__((address_space(1))) void*)(srcB[GG] + (TT) * 64),       \
        (__attribute__((address_space(3))) void*)(lds + 8192 + (GG) * 4096 + (w & 1) * 2048 + (w >> 1) * 512 + lane * 8), 16, 0, 0)

#define GS_MFMA(GG)                                                                  \
    do {                                                                             \
        __builtin_amdgcn_s_setprio(1);                                               \
        _Pragma("unroll")                                                            \
        for (int ks = 0; ks < 2; ++ks)                                               \
            _Pragma("unroll")                                                        \
            for (int mf = 0; mf < 2; ++mf)                                           \
                _Pragma("unroll")                                                    \
                for (int sub = 0; sub < 2; ++sub)                                    \
                    acc[mf][(GG) * 2 + sub] = __builtin_amdgcn_mfma_f32_16x16x32_bf16( \
                        aF[ks][mf], bF[ks][sub], acc[mf][(GG) * 2 + sub], 0, 0, 0);  \
        __builtin_amdgcn_s_setprio(0);                                               \
    } while (0)

#define GS_READ_A_B0()                                                               \
    do {                                                                             \
        _Pragma("unroll")                                                            \
        for (int ks = 0; ks < 2; ++ks) {                                             \
            _Pragma("unroll")                                                        \
            for (int mf = 0; mf < 2; ++mf)                                           \
                aF[ks][mf] = *(const short8*)&lds[rA[mf] + ks * 4096];               \
            _Pragma("unroll")                                                        \
            for (int sub = 0; sub < 2; ++sub)                                        \
                bF[ks][sub] = *(const short8*)&lds[8192 + ks * 2048 + rB[sub]];      \
        }                                                                            \
    } while (0)

#define GS_READ_B(GG)                                                                \
    do {                                                                             \
        _Pragma("unroll")                                                            \
        for (int ks = 0; ks < 2; ++ks)                                               \
            _Pragma("unroll")                                                        \
            for (int sub = 0; sub < 2; ++sub)                                        \
                bF[ks][sub] = *(const short8*)&lds[8192 + (GG) * 4096 + ks * 2048 + rB[sub]]; \
    } while (0)

    // prologue: stage A(0), B0..B3(0)  (B4(0) staged inside t=0 P0)
    GS_STG_A(0);
    GS_STG_B(0, 0); GS_STG_B(0, 1); GS_STG_B(0, 2); GS_STG_B(0, 3);

    short8 aF[2][2], bF[2][2];
    for (int t = 0; t < NT - 1; ++t) {
        GP_WAIT(3);
        GS_READ_A_B0();
        GS_STG_B(t, 4);
        GS_MFMA(0);
        GP_WAIT(3);
        GS_READ_B(1);
        GS_STG_A(t + 1);
        GS_MFMA(1);
        GP_WAIT(4);
        GS_READ_B(2);
        GS_STG_B(t + 1, 0);
        GS_MFMA(2);
        GP_WAIT(4);
        GS_READ_B(3);
        GS_STG_B(t + 1, 1);
        GS_MFMA(3);
        GP_WAIT(4);
        GS_READ_B(4);
        GS_STG_B(t + 1, 2);
        GS_STG_B(t + 1, 3);
        GS_MFMA(4);
    }
    // peeled last tile (works for any NT >= 1)
    GP_WAIT(3);
    GS_READ_A_B0();
    GS_STG_B(NT - 1, 4);
    GS_MFMA(0);
    GP_WAIT(3);
    GS_READ_B(1);
    GS_MFMA(1);
    GP_WAIT(2);
    GS_READ_B(2);
    GS_MFMA(2);
    GP_WAIT(1);
    GS_READ_B(3);
    GS_MFMA(3);
    GP_WAIT(0);
    GS_READ_B(4);
    GS_MFMA(4);

#undef GS_STG_A
#undef GS_STG_B
#undef GS_MFMA
#undef GS_READ_A_B0
#undef GS_READ_B

    int dsub[2];
#pragma unroll
    for (int sub = 0; sub < 2; ++sub)
        dsub[sub] = d0 + wd * 32 + sub * 16 + (lane & 15);
#pragma unroll
    for (int mf = 0; mf < 2; ++mf) {
#pragma unroll
        for (int rr = 0; rr < 4; ++rr) {
            int row = wm * 32 + mf * 16 + (lane >> 4) * 4 + rr;
            long J = rowTile + row;
            if (J < mLim) {
                long pb = ((long)ksx * mPad + J) * NTOT;
#pragma unroll
                for (int g = 0; g < 5; ++g)
#pragma unroll
                    for (int sub = 0; sub < 2; ++sub)
                        P[pb + g * 1024 + dsub[sub]] = acc[mf][g * 2 + sub][rr];
            }
        }
    }
}

// ---- reduce split-K partials + gate math ----
__global__ void redgate(const float* __restrict__ P, const float* __restrict__ bio,
                        const float* __restrict__ bfl, const float* __restrict__ bfr,
                        const void* __restrict__ c_in, void* __restrict__ c_out, int c_bf16,
                        float* __restrict__ outF, u16* __restrict__ hnext,
                        int lp, int level_off, int mc, int KS, int mPad) {
    int idx = blockIdx.x * 256 + threadIdx.x;
    int j = idx >> 8;
    if (j >= mc) return;
    int d = (idx & 255) * 4;
    int b = j >> lp, p = j & ((1 << lp) - 1);
    float ac[5][4] = {};
    for (int s = 0; s < KS; ++s) {
        long pb = ((long)s * mPad + j) * NTOT + d;
#pragma unroll
        for (int g = 0; g < 5; ++g) {
            float4 v = *(const float4*)&P[pb + g * 1024];
            ac[g][0] += v.x; ac[g][1] += v.y; ac[g][2] += v.z; ac[g][3] += v.w;
        }
    }
    float4 bi = *(const float4*)&bio[d];
    float4 bo = *(const float4*)&bio[1024 + d];
    float4 bc = *(const float4*)&bio[2048 + d];
    float4 bl = *(const float4*)&bfl[d];
    float4 br = *(const float4*)&bfr[d];
    const float* fbi = (const float*)&bi; const float* fbo = (const float*)&bo;
    const float* fbc = (const float*)&bc; const float* fbl = (const float*)&bl;
    const float* fbr = (const float*)&br;
    float clv[4], crv[4];
    {
        long cb = ((long)b * (2 << lp) + 2 * p) * H + d;
        if (c_bf16) {
            uint2 ul = *(const uint2*)((const u16*)c_in + cb);
            uint2 ur = *(const uint2*)((const u16*)c_in + cb + H);
            clv[0] = bf2f((u16)ul.x); clv[1] = bf2f((u16)(ul.x >> 16));
            clv[2] = bf2f((u16)ul.y); clv[3] = bf2f((u16)(ul.y >> 16));
            crv[0] = bf2f((u16)ur.x); crv[1] = bf2f((u16)(ur.x >> 16));
            crv[2] = bf2f((u16)ur.y); crv[3] = bf2f((u16)(ur.y >> 16));
        } else {
            float4 l4 = *(const float4*)((const float*)c_in + cb);
            float4 r4 = *(const float4*)((const float*)c_in + cb + H);
            clv[0] = l4.x; clv[1] = l4.y; clv[2] = l4.z; clv[3] = l4.w;
            crv[0] = r4.x; crv[1] = r4.y; crv[2] = r4.z; crv[3] = r4.w;
        }
    }
    float cv[4], hv[4];
#pragma unroll
    for (int qq = 0; qq < 4; ++qq) {
        float c = sigf(ac[0][qq] + fbi[qq]) * tanh_(ac[2][qq] + fbc[qq]);
        c += sigf(ac[3][qq] + fbl[qq]) * clv[qq] + sigf(ac[4][qq] + fbr[qq]) * crv[qq];
        cv[qq] = c;
        hv[qq] = sigf(ac[1][qq] + fbo[qq]) * tanh_(c);
    }
    long co = (long)j * H + d;
    if (c_bf16) {
        uint2 oc; oc.x = pk2(cv[0], cv[1]); oc.y = pk2(cv[2], cv[3]);
        *(uint2*)((u16*)c_out + co) = oc;
    } else {
        *(float4*)((float*)c_out + co) = make_float4(cv[0], cv[1], cv[2], cv[3]);
    }
    long oi = ((long)b * 255 + level_off + p) * H + d;
    *(float4*)&outF[oi] = make_float4(hv[0], hv[1], hv[2], hv[3]);
    uint2 oh; oh.x = pk2(hv[0], hv[1]); oh.y = pk2(hv[2], hv[3]);
    *(uint2*)(hnext + (long)j * H + d) = oh;
}

// ---- gates (legacy fallback path) ----
__global__ void gates(const float* __restrict__ G, const float* __restrict__ bio,
                      const float* __restrict__ bfl, const float* __restrict__ bfr,
                      const void* __restrict__ c_in, void* __restrict__ c_out, int c_bf16,
                      float* __restrict__ outF, u16* __restrict__ hnext,
                      int lp, int level_off, int row0, int mc) {
    int idx = blockIdx.x * 256 + threadIdx.x;
    int j = idx >> 8;
    if (j >= mc) return;
    int d = (idx & 255) * 4;
    int J = row0 + j;
    int b = J >> lp, p = J & ((1 << lp) - 1);
    long gb = (long)j * NTOT;
    float4 gi = *(const float4*)&G[gb + d];
    float4 go = *(const float4*)&G[gb + 1024 + d];
    float4 gc = *(const float4*)&G[gb + 2048 + d];
    float4 gl = *(const float4*)&G[gb + 3072 + d];
    float4 gr = *(const float4*)&G[gb + 4096 + d];
    float4 bi = *(const float4*)&bio[d];
    float4 bo = *(const float4*)&bio[1024 + d];
    float4 bc = *(const float4*)&bio[2048 + d];
    float4 bl = *(const float4*)&bfl[d];
    float4 br = *(const float4*)&bfr[d];
    float clv[4] = {0.f, 0.f, 0.f, 0.f}, crv[4] = {0.f, 0.f, 0.f, 0.f};
    if (c_in) {
        long cb = ((long)b * (2 << lp) + 2 * p) * H + d;
        if (c_bf16) {
            uint2 ul = *(const uint2*)((const u16*)c_in + cb);
            uint2 ur = *(const uint2*)((const u16*)c_in + cb + H);
            clv[0] = bf2f((u16)ul.x); clv[1] = bf2f((u16)(ul.x >> 16));
            clv[2] = bf2f((u16)ul.y); clv[3] = bf2f((u16)(ul.y >> 16));
            crv[0] = bf2f((u16)ur.x); crv[1] = bf2f((u16)(ur.x >> 16));
            crv[2] = bf2f((u16)ur.y); crv[3] = bf2f((u16)(ur.y >> 16));
        } else {
            float4 l4 = *(const float4*)((const float*)c_in + cb);
            float4 r4 = *(const float4*)((const float*)c_in + cb + H);
            clv[0] = l4.x; clv[1] = l4.y; clv[2] = l4.z; clv[3] = l4.w;
            crv[0] = r4.x; crv[1] = r4.y; crv[2] = r4.z; crv[3] = r4.w;
        }
    }
    const float* fgi = (const float*)&gi; const float* fgo = (const float*)&go;
    const float* fgc = (const float*)&gc; const float* fgl = (const float*)&gl;
    const float* fgr = (const float*)&gr;
    const float* fbi = (const float*)&bi; const float* fbo = (const float*)&bo;
    const float* fbc = (const float*)&bc; const float* fbl = (const float*)&bl;
    const float* fbr = (const float*)&br;
    float cv[4], hv[4];
    int has_c = (c_in != nullptr);
#pragma unroll
    for (int qq = 0; qq < 4; ++qq) {
        float c = sigf(fgi[qq] + fbi[qq]) * tanh_(fgc[qq] + fbc[qq]);
        if (has_c)
            c += sigf(fgl[qq] + fbl[qq]) * clv[qq] + sigf(fgr[qq] + fbr[qq]) * crv[qq];
        cv[qq] = c;
        hv[qq] = sigf(fgo[qq] + fbo[qq]) * tanh_(c);
    }
    long co = (long)J * H + d;
    if (c_bf16) {
        uint2 oc; oc.x = pk2(cv[0], cv[1]); oc.y = pk2(cv[2], cv[3]);
        *(uint2*)((u16*)c_out + co) = oc;
    } else {
        *(float4*)((float*)c_out + co) = make_float4(cv[0], cv[1], cv[2], cv[3]);
    }
    long oi = ((long)b * 255 + level_off + p) * H + d;
    *(float4*)&outF[oi] = make_float4(hv[0], hv[1], hv[2], hv[3]);
    uint2 oh; oh.x = pk2(hv[0], hv[1]); oh.y = pk2(hv[2], hv[3]);
    *(uint2*)(hnext + (long)J * H + d) = oh;
}

__global__ void root_copy(const float* __restrict__ outF, const void* __restrict__ c_root,
                          int c_bf16, float* __restrict__ tail) {
    int idx = blockIdx.x * 256 + threadIdx.x;   // 131072
    if (idx < 65536) {
        int b = idx >> 10, d = idx & 1023;
        tail[idx] = outF[((long)b * 255 + 254) * H + d];
    } else {
        int i2 = idx - 65536;
        tail[idx] = c_bf16 ? bf2f(((const u16*)c_root)[i2]) : ((const float*)c_root)[i2];
    }
}

extern "C" void kernel_launch(void* const* d_in, const int* in_sizes, int n_in,
                              void* d_out, int out_size, void* d_ws, size_t ws_size,
                              hipStream_t stream) {
    const int* tokens = (const int*)d_in[0];
    const float* emb = (const float*)d_in[1];
    const float* Wio = (const float*)d_in[2];
    const float* bio = (const float*)d_in[3];
    const float* Uio = (const float*)d_in[4];
    const float* Wfl = (const float*)d_in[5];
    const float* bfl = (const float*)d_in[6];
    const float* Ufl = (const float*)d_in[7];
    const float* Wfr = (const float*)d_in[8];
    const float* bfr = (const float*)d_in[9];
    const float* Ufr = (const float*)d_in[10];
    float* outF = (float*)d_out;

    // ---- ws carve (adaptive) ----
    char* ws = (char*)d_ws;
    size_t off = 0;
    u16* WT   = (u16*)(ws + off); off += (size_t)NTOT * K2 * 2;        // 20.97 MB
    u16* leaf = (u16*)(ws + off); off += (size_t)BATCH * 256 * H * 2;  // 33.55 MB
    u16* hE   = (u16*)(ws + off); off += (size_t)8192 * H * 2;         // 16.78 MB
    u16* hO   = (u16*)(ws + off); off += (size_t)4096 * H * 2;         //  8.39 MB
    size_t cEf = (size_t)8192 * H, cOf = (size_t)4096 * H;             // elements
    int c_bf16 = (ws_size >= off + (cEf + cOf) * 4 + (size_t)512 * NTOT * 4) ? 0 : 1;
    size_t csz = c_bf16 ? 2 : 4;
    void* cE = (void*)(ws + off); off += cEf * csz;
    void* cO = (void*)(ws + off); off += cOf * csz;
    size_t avail = (ws_size > off) ? (ws_size - off) : 0;
    // split-K partial buffer: 2048 rows x 5120 fp32 = 41.9 MB (overlaps legacy G)
    size_t Pbytes = (size_t)2048 * NTOT * 4;
    int splitOK = (avail >= Pbytes);
    float* P = (float*)(ws + off);
    long Grows = (long)(avail / ((size_t)NTOT * 4));
    if (Grows > 512) Grows = 512;           // legacy path only handles m <= 512
    Grows &= ~127L;
    if (Grows < 128) Grows = 128;
    float* G = (float*)(ws + off);

    fuse_pre<<<26624, 256, 0, stream>>>(Wio, Uio, Wfl, Ufl, Wfr, Ufr, WT,
                                        tokens, emb, leaf);

    const int off_out[8] = {0, 128, 192, 224, 240, 248, 252, 254};
    for (int li = 0; li < 8; ++li) {
        int lp = 7 - li;
        long m = (long)BATCH << lp;
        const u16* Acur = (li == 0) ? leaf : ((li & 1) ? hE : hO);
        u16* hnext = (li & 1) ? hO : hE;
        const void* c_in = (li == 0) ? nullptr : ((li & 1) ? cE : cO);
        void* c_out = (li & 1) ? cO : cE;
        if (m >= 2048) {
            int gm = (int)(m >> 7);
            gemmP128<<<gm * 16, 512, 0, stream>>>(Acur, WT, bio, bfl, bfr,
                                                  c_in, c_out, c_bf16, outF, hnext,
                                                  lp, off_out[li], gm);
        } else if (splitOK) {
            int KS = (m == 1024) ? 2 : (m == 512) ? 4 : (m == 256) ? 8 : 16;
            int RT = (m >= 128) ? (int)(m >> 7) : 1;
            int mPad = RT * 128;
            int NT = 32 / KS;
            gemmS<<<RT * 16 * KS, 512, 0, stream>>>(Acur, WT, P, RT, KS, NT,
                                                    (int)m, mPad);
            redgate<<<(int)m, 256, 0, stream>>>(P, bio, bfl, bfr, c_in, c_out, c_bf16,
                                                outF, hnext, lp, off_out[li],
                                                (int)m, KS, mPad);
        } else {
            for (long row0 = 0; row0 < m; row0 += Grows) {
                int mc = (int)((m - row0 > Grows) ? Grows : (m - row0));
                dim3 grid((mc + BM - 1) / BM, NTOT / BN);
                gemm_bt<<<grid, 256, 0, stream>>>(Acur + row0 * K2, WT, G, mc);
                gates<<<mc, 256, 0, stream>>>(G, bio, bfl, bfr, c_in, c_out, c_bf16,
                                              outF, hnext, lp, off_out[li], (int)row0, mc);
            }
        }
    }
    root_copy<<<512, 256, 0, stream>>>(outF, cO, c_bf16, outF + (size_t)BATCH * 255 * H);
}